// Round 1
// baseline (1778.835 us; speedup 1.0000x reference)
//
#include <hip/hip_runtime.h>

#define D       128
#define NNODES  50000
#define NEDGES  600000
#define TE      32
#define BLK     256
#define LN_EPS  1e-5f

typedef float fx4 __attribute__((ext_vector_type(4)));

__device__ __forceinline__ float silu_f(float z) {
    return z * (1.0f / (1.0f + __expf(-z)));
}

// ---------------------------------------------------------------------------
// Edge kernel: per 32-edge tile
//   in = [x[dst], x[src], edge_attr]  (384)
//   h1 = silu(in @ W1 + b1)           (128)
//   h2 = h1 @ W2 + b2                 (128)
//   e_new = LN(h2) * g + b
//   edges_out[e] = e_new ; atomicAdd(agg[dst[e]], e_new)
// ---------------------------------------------------------------------------
__global__ __launch_bounds__(BLK) void edge_kernel(
    const float* __restrict__ x,
    const float* __restrict__ edge_attr,
    const int*   __restrict__ edge_index,
    const float* __restrict__ W1, const float* __restrict__ b1,
    const float* __restrict__ W2, const float* __restrict__ b2,
    const float* __restrict__ lng, const float* __restrict__ lnb,
    float* __restrict__ edges_out,
    float* __restrict__ agg)
{
    __shared__ float in_t[TE][392];   // 384 used, rows 16B-aligned
    __shared__ float h1_t[TE][132];   // 128 used
    __shared__ int   src_s[TE], dst_s[TE];

    const int tid = threadIdx.x;
    const int e0g = blockIdx.x * TE;

    if (tid < TE) {
        src_s[tid] = edge_index[e0g + tid];            // edge_index[0] = src (j)
        dst_s[tid] = edge_index[NEDGES + e0g + tid];   // edge_index[1] = dst (i)
    }
    __syncthreads();

    // stage A-tile: 32 rows x 96 float4
    for (int idx = tid; idx < TE * 96; idx += BLK) {
        const int e   = idx / 96;
        const int c   = idx % 96;
        const int seg = c >> 5;
        const int c4  = (c & 31) << 2;
        const float* p;
        if (seg == 0)      p = x + (size_t)dst_s[e] * D + c4;
        else if (seg == 1) p = x + (size_t)src_s[e] * D + c4;
        else               p = edge_attr + (size_t)(e0g + e) * D + c4;
        *(fx4*)&in_t[e][seg * 128 + c4] = *(const fx4*)p;
    }
    __syncthreads();

    const int tx = tid & 31;
    const int ty = tid >> 5;
    const int n0 = tx << 2;   // output column group
    const int e0 = ty << 2;   // edge-row group

    // ---- GEMM1: [32,384] @ [384,128] ----
    float acc[4][4];
    #pragma unroll
    for (int i = 0; i < 4; ++i)
        #pragma unroll
        for (int j = 0; j < 4; ++j) acc[i][j] = 0.0f;

    for (int k0 = 0; k0 < 3 * D; k0 += 4) {
        fx4 a[4], w[4];
        #pragma unroll
        for (int i = 0; i < 4; ++i) a[i] = *(const fx4*)&in_t[e0 + i][k0];
        #pragma unroll
        for (int r = 0; r < 4; ++r) w[r] = *(const fx4*)&W1[(size_t)(k0 + r) * D + n0];
        #pragma unroll
        for (int i = 0; i < 4; ++i)
            #pragma unroll
            for (int r = 0; r < 4; ++r)
                #pragma unroll
                for (int j = 0; j < 4; ++j)
                    acc[i][j] += a[i][r] * w[r][j];
    }

    {
        fx4 bias1 = *(const fx4*)&b1[n0];
        #pragma unroll
        for (int i = 0; i < 4; ++i) {
            fx4 h;
            #pragma unroll
            for (int j = 0; j < 4; ++j) h[j] = silu_f(acc[i][j] + bias1[j]);
            *(fx4*)&h1_t[e0 + i][n0] = h;
        }
    }
    __syncthreads();

    // ---- GEMM2: [32,128] @ [128,128] ----
    float acc2[4][4];
    #pragma unroll
    for (int i = 0; i < 4; ++i)
        #pragma unroll
        for (int j = 0; j < 4; ++j) acc2[i][j] = 0.0f;

    for (int k0 = 0; k0 < D; k0 += 4) {
        fx4 a[4], w[4];
        #pragma unroll
        for (int i = 0; i < 4; ++i) a[i] = *(const fx4*)&h1_t[e0 + i][k0];
        #pragma unroll
        for (int r = 0; r < 4; ++r) w[r] = *(const fx4*)&W2[(size_t)(k0 + r) * D + n0];
        #pragma unroll
        for (int i = 0; i < 4; ++i)
            #pragma unroll
            for (int r = 0; r < 4; ++r)
                #pragma unroll
                for (int j = 0; j < 4; ++j)
                    acc2[i][j] += a[i][r] * w[r][j];
    }

    // ---- bias + LayerNorm + store + scatter-add ----
    {
        fx4 b2v = *(const fx4*)&b2[n0];
        fx4 gv  = *(const fx4*)&lng[n0];
        fx4 bv  = *(const fx4*)&lnb[n0];
        #pragma unroll
        for (int i = 0; i < 4; ++i) {
            float z[4];
            float s = 0.0f, q = 0.0f;
            #pragma unroll
            for (int j = 0; j < 4; ++j) {
                z[j] = acc2[i][j] + b2v[j];
                s += z[j];
                q += z[j] * z[j];
            }
            #pragma unroll
            for (int m = 1; m <= 16; m <<= 1) {
                s += __shfl_xor(s, m, 64);
                q += __shfl_xor(q, m, 64);
            }
            const float mu   = s * (1.0f / 128.0f);
            const float var  = q * (1.0f / 128.0f) - mu * mu;
            const float rstd = rsqrtf(var + LN_EPS);
            fx4 o;
            #pragma unroll
            for (int j = 0; j < 4; ++j) o[j] = (z[j] - mu) * rstd * gv[j] + bv[j];

            const int er = e0 + i;
            *(fx4*)&edges_out[(size_t)(e0g + er) * D + n0] = o;
            float* ap = agg + (size_t)dst_s[er] * D + n0;
            #pragma unroll
            for (int j = 0; j < 4; ++j) atomicAdd(ap + j, o[j]);
        }
    }
}

// ---------------------------------------------------------------------------
// Node kernel: per 32-node tile
//   in = [x, agg]  (256)
//   nodes_out = LN(silu(in@W1+b1)@W2+b2)*g + b + x
//   (agg lives in the same buffer as nodes_out; each block reads its own rows
//    into LDS before overwriting them)
// ---------------------------------------------------------------------------
__global__ __launch_bounds__(BLK) void node_kernel(
    const float* __restrict__ x,
    const float* __restrict__ agg,
    const float* __restrict__ W1, const float* __restrict__ b1,
    const float* __restrict__ W2, const float* __restrict__ b2,
    const float* __restrict__ lng, const float* __restrict__ lnb,
    float* __restrict__ nodes_out)
{
    __shared__ float in_t[TE][264];   // 256 used
    __shared__ float h1_t[TE][132];   // 128 used

    const int tid = threadIdx.x;
    const int r0g = blockIdx.x * TE;

    for (int idx = tid; idx < TE * 64; idx += BLK) {
        const int e   = idx / 64;
        const int c   = idx % 64;
        const int seg = c >> 5;
        const int c4  = (c & 31) << 2;
        const int row = r0g + e;
        fx4 v = {0.0f, 0.0f, 0.0f, 0.0f};
        if (row < NNODES) {
            const float* p = (seg == 0) ? (x + (size_t)row * D + c4)
                                        : (agg + (size_t)row * D + c4);
            v = *(const fx4*)p;
        }
        *(fx4*)&in_t[e][seg * 128 + c4] = v;
    }
    __syncthreads();

    const int tx = tid & 31;
    const int ty = tid >> 5;
    const int n0 = tx << 2;
    const int e0 = ty << 2;

    // ---- GEMM1: [32,256] @ [256,128] ----
    float acc[4][4];
    #pragma unroll
    for (int i = 0; i < 4; ++i)
        #pragma unroll
        for (int j = 0; j < 4; ++j) acc[i][j] = 0.0f;

    for (int k0 = 0; k0 < 2 * D; k0 += 4) {
        fx4 a[4], w[4];
        #pragma unroll
        for (int i = 0; i < 4; ++i) a[i] = *(const fx4*)&in_t[e0 + i][k0];
        #pragma unroll
        for (int r = 0; r < 4; ++r) w[r] = *(const fx4*)&W1[(size_t)(k0 + r) * D + n0];
        #pragma unroll
        for (int i = 0; i < 4; ++i)
            #pragma unroll
            for (int r = 0; r < 4; ++r)
                #pragma unroll
                for (int j = 0; j < 4; ++j)
                    acc[i][j] += a[i][r] * w[r][j];
    }

    {
        fx4 bias1 = *(const fx4*)&b1[n0];
        #pragma unroll
        for (int i = 0; i < 4; ++i) {
            fx4 h;
            #pragma unroll
            for (int j = 0; j < 4; ++j) h[j] = silu_f(acc[i][j] + bias1[j]);
            *(fx4*)&h1_t[e0 + i][n0] = h;
        }
    }
    __syncthreads();

    // ---- GEMM2: [32,128] @ [128,128] ----
    float acc2[4][4];
    #pragma unroll
    for (int i = 0; i < 4; ++i)
        #pragma unroll
        for (int j = 0; j < 4; ++j) acc2[i][j] = 0.0f;

    for (int k0 = 0; k0 < D; k0 += 4) {
        fx4 a[4], w[4];
        #pragma unroll
        for (int i = 0; i < 4; ++i) a[i] = *(const fx4*)&h1_t[e0 + i][k0];
        #pragma unroll
        for (int r = 0; r < 4; ++r) w[r] = *(const fx4*)&W2[(size_t)(k0 + r) * D + n0];
        #pragma unroll
        for (int i = 0; i < 4; ++i)
            #pragma unroll
            for (int r = 0; r < 4; ++r)
                #pragma unroll
                for (int j = 0; j < 4; ++j)
                    acc2[i][j] += a[i][r] * w[r][j];
    }

    // ---- bias + LayerNorm + residual + store ----
    {
        fx4 b2v = *(const fx4*)&b2[n0];
        fx4 gv  = *(const fx4*)&lng[n0];
        fx4 bv  = *(const fx4*)&lnb[n0];
        #pragma unroll
        for (int i = 0; i < 4; ++i) {
            const int row = r0g + e0 + i;
            float z[4];
            float s = 0.0f, q = 0.0f;
            #pragma unroll
            for (int j = 0; j < 4; ++j) {
                z[j] = acc2[i][j] + b2v[j];
                s += z[j];
                q += z[j] * z[j];
            }
            #pragma unroll
            for (int m = 1; m <= 16; m <<= 1) {
                s += __shfl_xor(s, m, 64);
                q += __shfl_xor(q, m, 64);
            }
            const float mu   = s * (1.0f / 128.0f);
            const float var  = q * (1.0f / 128.0f) - mu * mu;
            const float rstd = rsqrtf(var + LN_EPS);
            if (row < NNODES) {
                fx4 xr = *(const fx4*)&x[(size_t)row * D + n0];
                fx4 o;
                #pragma unroll
                for (int j = 0; j < 4; ++j)
                    o[j] = (z[j] - mu) * rstd * gv[j] + bv[j] + xr[j];
                *(fx4*)&nodes_out[(size_t)row * D + n0] = o;
            }
        }
    }
}

extern "C" void kernel_launch(void* const* d_in, const int* in_sizes, int n_in,
                              void* d_out, int out_size, void* d_ws, size_t ws_size,
                              hipStream_t stream) {
    (void)in_sizes; (void)n_in; (void)d_ws; (void)ws_size; (void)out_size;

    const float* x         = (const float*)d_in[0];
    const float* edge_attr = (const float*)d_in[1];
    const int*   edge_idx  = (const int*)  d_in[2];
    const float* eW1 = (const float*)d_in[3];
    const float* eb1 = (const float*)d_in[4];
    const float* eW2 = (const float*)d_in[5];
    const float* eb2 = (const float*)d_in[6];
    const float* elg = (const float*)d_in[7];
    const float* elb = (const float*)d_in[8];
    const float* nW1 = (const float*)d_in[9];
    const float* nb1 = (const float*)d_in[10];
    const float* nW2 = (const float*)d_in[11];
    const float* nb2 = (const float*)d_in[12];
    const float* nlg = (const float*)d_in[13];
    const float* nlb = (const float*)d_in[14];

    float* out       = (float*)d_out;
    float* nodes_out = out;                        // doubles as agg accumulator
    float* edges_out = out + (size_t)NNODES * D;

    // zero the aggregation region (nodes_out) — deterministic each launch
    hipMemsetAsync(nodes_out, 0, (size_t)NNODES * D * sizeof(float), stream);

    edge_kernel<<<NEDGES / TE, BLK, 0, stream>>>(
        x, edge_attr, edge_idx, eW1, eb1, eW2, eb2, elg, elb,
        edges_out, nodes_out);

    node_kernel<<<(NNODES + TE - 1) / TE, BLK, 0, stream>>>(
        x, nodes_out, nW1, nb1, nW2, nb2, nlg, nlb,
        nodes_out);
}

// Round 2
// 891.425 us; speedup vs baseline: 1.9955x; 1.9955x over previous
//
#include <hip/hip_runtime.h>

#define D       128
#define NNODES  50000
#define NEDGES  600000
#define TE      64
#define BLK     256
#define LN_EPS  1e-5f

typedef float  fx4    __attribute__((ext_vector_type(4)));
typedef float  f32x4  __attribute__((ext_vector_type(4)));
typedef __bf16 bf16x4 __attribute__((ext_vector_type(4)));
typedef __bf16 bf16x8 __attribute__((ext_vector_type(8)));

// d_ws layout (bf16 elements)
#define EW1T_OFF 0                         // [128][384]
#define EW2T_OFF (128 * 384)               // [128][128]
#define NW1T_OFF (EW2T_OFF + 128 * 128)    // [128][256]
#define NW2T_OFF (NW1T_OFF + 128 * 256)    // [128][128]
#define WS_ELEMS (NW2T_OFF + 128 * 128)    // 114688 bf16

__device__ __forceinline__ float silu_f(float z) {
    return z * (1.0f / (1.0f + __expf(-z)));
}

// ---------------------------------------------------------------------------
// Weight prep: transpose + f32->bf16.  out[n][k] = in[k][n]  (N=128 always)
// ---------------------------------------------------------------------------
__global__ __launch_bounds__(256) void prep_weights(
    const float* __restrict__ eW1, const float* __restrict__ eW2,
    const float* __restrict__ nW1, const float* __restrict__ nW2,
    __bf16* __restrict__ ws)
{
    int idx = blockIdx.x * 256 + threadIdx.x;
    if (idx >= WS_ELEMS) return;
    const float* src;
    int K, local;
    if (idx < EW2T_OFF)      { src = eW1; K = 384; local = idx; }
    else if (idx < NW1T_OFF) { src = eW2; K = 128; local = idx - EW2T_OFF; }
    else if (idx < NW2T_OFF) { src = nW1; K = 256; local = idx - NW1T_OFF; }
    else                     { src = nW2; K = 128; local = idx - NW2T_OFF; }
    int n = local / K, k = local % K;
    ws[idx] = (__bf16)src[(size_t)k * D + n];
}

// ---------------------------------------------------------------------------
// Edge kernel (bf16 MFMA): 64 edges/block, 4 waves, 16 rows each.
// ---------------------------------------------------------------------------
__global__ __launch_bounds__(BLK) void edge_kernel(
    const float* __restrict__ x,
    const float* __restrict__ edge_attr,
    const int*   __restrict__ edge_index,
    const __bf16* __restrict__ W1T,   // [128][384]
    const float* __restrict__ b1,
    const __bf16* __restrict__ W2T,   // [128][128]
    const float* __restrict__ b2,
    const float* __restrict__ lng, const float* __restrict__ lnb,
    float* __restrict__ edges_out,
    float* __restrict__ agg)
{
    __shared__ __bf16 in_t[TE][392];   // 384 used; 196 words/row = 4 mod 32
    __shared__ __bf16 h1_t[TE][136];   // 128 used; 68 words/row  = 4 mod 32
    __shared__ int    src_s[TE], dst_s[TE];

    const int tid = threadIdx.x;
    const int e0g = blockIdx.x * TE;

    if (tid < TE) {
        src_s[tid] = edge_index[e0g + tid];            // edge_index[0] = src (j)
        dst_s[tid] = edge_index[NEDGES + e0g + tid];   // edge_index[1] = dst (i)
    }
    __syncthreads();

    // stage A-tile: 64 rows x 96 float4 -> bf16 LDS
    for (int idx = tid; idx < TE * 96; idx += BLK) {
        const int e   = idx / 96;
        const int c   = idx % 96;
        const int seg = c >> 5;
        const int c4  = (c & 31) << 2;
        const float* p;
        if (seg == 0)      p = x + (size_t)dst_s[e] * D + c4;
        else if (seg == 1) p = x + (size_t)src_s[e] * D + c4;
        else               p = edge_attr + (size_t)(e0g + e) * D + c4;
        fx4 v = *(const fx4*)p;
        bf16x4 h;
        #pragma unroll
        for (int j = 0; j < 4; ++j) h[j] = (__bf16)v[j];
        *(bf16x4*)&in_t[e][seg * 128 + c4] = h;
    }
    __syncthreads();

    const int lane  = tid & 63;
    const int wid   = tid >> 6;
    const int wrow0 = wid << 4;        // wave's 16 rows
    const int c16   = lane & 15;
    const int kq    = lane >> 4;       // 0..3
    const int ks8   = kq << 3;         // k-slot offset

    // ---- GEMM1: [16,384] @ [384,128] per wave ----
    f32x4 acc[8];
    #pragma unroll
    for (int nf = 0; nf < 8; ++nf) acc[nf] = (f32x4){0.f, 0.f, 0.f, 0.f};

    #pragma unroll
    for (int k0 = 0; k0 < 3 * D; k0 += 32) {
        bf16x8 a = *(const bf16x8*)&in_t[wrow0 + c16][k0 + ks8];
        #pragma unroll
        for (int nf = 0; nf < 8; ++nf) {
            bf16x8 b = *(const bf16x8*)&W1T[(size_t)(nf * 16 + c16) * 384 + k0 + ks8];
            acc[nf] = __builtin_amdgcn_mfma_f32_16x16x32_bf16(a, b, acc[nf], 0, 0, 0);
        }
    }

    // SiLU + bias -> h1 LDS tile (wave-private rows: no barrier needed)
    #pragma unroll
    for (int nf = 0; nf < 8; ++nf) {
        const float bb = b1[nf * 16 + c16];
        #pragma unroll
        for (int r = 0; r < 4; ++r) {
            float h = silu_f(acc[nf][r] + bb);
            h1_t[wrow0 + kq * 4 + r][nf * 16 + c16] = (__bf16)h;
        }
    }

    // ---- GEMM2: [16,128] @ [128,128] per wave ----
    f32x4 acc2[8];
    #pragma unroll
    for (int nf = 0; nf < 8; ++nf) acc2[nf] = (f32x4){0.f, 0.f, 0.f, 0.f};

    #pragma unroll
    for (int k0 = 0; k0 < D; k0 += 32) {
        bf16x8 a = *(const bf16x8*)&h1_t[wrow0 + c16][k0 + ks8];
        #pragma unroll
        for (int nf = 0; nf < 8; ++nf) {
            bf16x8 b = *(const bf16x8*)&W2T[(size_t)(nf * 16 + c16) * 128 + k0 + ks8];
            acc2[nf] = __builtin_amdgcn_mfma_f32_16x16x32_bf16(a, b, acc2[nf], 0, 0, 0);
        }
    }

    // ---- bias + LayerNorm + store + scatter-add ----
    float b2v[8], gv[8], bvv[8];
    #pragma unroll
    for (int nf = 0; nf < 8; ++nf) {
        b2v[nf] = b2[nf * 16 + c16];
        gv[nf]  = lng[nf * 16 + c16];
        bvv[nf] = lnb[nf * 16 + c16];
    }

    float z[8][4];
    float s[4] = {0.f, 0.f, 0.f, 0.f}, q[4] = {0.f, 0.f, 0.f, 0.f};
    #pragma unroll
    for (int nf = 0; nf < 8; ++nf)
        #pragma unroll
        for (int r = 0; r < 4; ++r) {
            float zz = acc2[nf][r] + b2v[nf];
            z[nf][r] = zz;
            s[r] += zz;
            q[r] += zz * zz;
        }
    #pragma unroll
    for (int m = 1; m <= 8; m <<= 1)
        #pragma unroll
        for (int r = 0; r < 4; ++r) {
            s[r] += __shfl_xor(s[r], m, 64);
            q[r] += __shfl_xor(q[r], m, 64);
        }
    float mu[4], rstd[4];
    #pragma unroll
    for (int r = 0; r < 4; ++r) {
        mu[r] = s[r] * (1.0f / 128.0f);
        float var = q[r] * (1.0f / 128.0f) - mu[r] * mu[r];
        rstd[r] = rsqrtf(var + LN_EPS);
    }

    #pragma unroll
    for (int r = 0; r < 4; ++r) {
        const int row = wrow0 + kq * 4 + r;         // row within tile
        const size_t erow = (size_t)(e0g + row) * D;
        float* ap = agg + (size_t)dst_s[row] * D;
        #pragma unroll
        for (int nf = 0; nf < 8; ++nf) {
            const int col = nf * 16 + c16;
            float o = (z[nf][r] - mu[r]) * rstd[r] * gv[nf] + bvv[nf];
            edges_out[erow + col] = o;
            atomicAdd(ap + col, o);
        }
    }
}

// ---------------------------------------------------------------------------
// Node kernel (bf16 MFMA): 64 nodes/block; in = [x, agg] (256)
// ---------------------------------------------------------------------------
__global__ __launch_bounds__(BLK) void node_kernel(
    const float* __restrict__ x,
    const float* __restrict__ agg,
    const __bf16* __restrict__ W1T,   // [128][256]
    const float* __restrict__ b1,
    const __bf16* __restrict__ W2T,   // [128][128]
    const float* __restrict__ b2,
    const float* __restrict__ lng, const float* __restrict__ lnb,
    float* __restrict__ nodes_out)
{
    __shared__ __bf16 in_t[TE][264];   // 256 used; 132 words/row = 4 mod 32
    __shared__ __bf16 h1_t[TE][136];

    const int tid = threadIdx.x;
    const int r0g = blockIdx.x * TE;

    for (int idx = tid; idx < TE * 64; idx += BLK) {
        const int e   = idx / 64;
        const int c   = idx % 64;
        const int seg = c >> 5;
        const int c4  = (c & 31) << 2;
        const int row = r0g + e;
        fx4 v = {0.f, 0.f, 0.f, 0.f};
        if (row < NNODES) {
            const float* p = (seg == 0) ? (x + (size_t)row * D + c4)
                                        : (agg + (size_t)row * D + c4);
            v = *(const fx4*)p;
        }
        bf16x4 h;
        #pragma unroll
        for (int j = 0; j < 4; ++j) h[j] = (__bf16)v[j];
        *(bf16x4*)&in_t[e][seg * 128 + c4] = h;
    }
    __syncthreads();

    const int lane  = tid & 63;
    const int wid   = tid >> 6;
    const int wrow0 = wid << 4;
    const int c16   = lane & 15;
    const int kq    = lane >> 4;
    const int ks8   = kq << 3;

    // ---- GEMM1: [16,256] @ [256,128] ----
    f32x4 acc[8];
    #pragma unroll
    for (int nf = 0; nf < 8; ++nf) acc[nf] = (f32x4){0.f, 0.f, 0.f, 0.f};

    #pragma unroll
    for (int k0 = 0; k0 < 2 * D; k0 += 32) {
        bf16x8 a = *(const bf16x8*)&in_t[wrow0 + c16][k0 + ks8];
        #pragma unroll
        for (int nf = 0; nf < 8; ++nf) {
            bf16x8 b = *(const bf16x8*)&W1T[(size_t)(nf * 16 + c16) * 256 + k0 + ks8];
            acc[nf] = __builtin_amdgcn_mfma_f32_16x16x32_bf16(a, b, acc[nf], 0, 0, 0);
        }
    }

    #pragma unroll
    for (int nf = 0; nf < 8; ++nf) {
        const float bb = b1[nf * 16 + c16];
        #pragma unroll
        for (int r = 0; r < 4; ++r) {
            float h = silu_f(acc[nf][r] + bb);
            h1_t[wrow0 + kq * 4 + r][nf * 16 + c16] = (__bf16)h;
        }
    }

    // ---- GEMM2 ----
    f32x4 acc2[8];
    #pragma unroll
    for (int nf = 0; nf < 8; ++nf) acc2[nf] = (f32x4){0.f, 0.f, 0.f, 0.f};

    #pragma unroll
    for (int k0 = 0; k0 < D; k0 += 32) {
        bf16x8 a = *(const bf16x8*)&h1_t[wrow0 + c16][k0 + ks8];
        #pragma unroll
        for (int nf = 0; nf < 8; ++nf) {
            bf16x8 b = *(const bf16x8*)&W2T[(size_t)(nf * 16 + c16) * 128 + k0 + ks8];
            acc2[nf] = __builtin_amdgcn_mfma_f32_16x16x32_bf16(a, b, acc2[nf], 0, 0, 0);
        }
    }

    // ---- bias + LN + residual + store ----
    float b2v[8], gv[8], bvv[8];
    #pragma unroll
    for (int nf = 0; nf < 8; ++nf) {
        b2v[nf] = b2[nf * 16 + c16];
        gv[nf]  = lng[nf * 16 + c16];
        bvv[nf] = lnb[nf * 16 + c16];
    }

    float z[8][4];
    float s[4] = {0.f, 0.f, 0.f, 0.f}, q[4] = {0.f, 0.f, 0.f, 0.f};
    #pragma unroll
    for (int nf = 0; nf < 8; ++nf)
        #pragma unroll
        for (int r = 0; r < 4; ++r) {
            float zz = acc2[nf][r] + b2v[nf];
            z[nf][r] = zz;
            s[r] += zz;
            q[r] += zz * zz;
        }
    #pragma unroll
    for (int m = 1; m <= 8; m <<= 1)
        #pragma unroll
        for (int r = 0; r < 4; ++r) {
            s[r] += __shfl_xor(s[r], m, 64);
            q[r] += __shfl_xor(q[r], m, 64);
        }
    float mu[4], rstd[4];
    #pragma unroll
    for (int r = 0; r < 4; ++r) {
        mu[r] = s[r] * (1.0f / 128.0f);
        float var = q[r] * (1.0f / 128.0f) - mu[r] * mu[r];
        rstd[r] = rsqrtf(var + LN_EPS);
    }

    #pragma unroll
    for (int r = 0; r < 4; ++r) {
        const int row = r0g + wrow0 + kq * 4 + r;
        if (row >= NNODES) continue;
        const size_t orow = (size_t)row * D;
        #pragma unroll
        for (int nf = 0; nf < 8; ++nf) {
            const int col = nf * 16 + c16;
            float o = (z[nf][r] - mu[r]) * rstd[r] * gv[nf] + bvv[nf] + x[orow + col];
            nodes_out[orow + col] = o;
        }
    }
}

extern "C" void kernel_launch(void* const* d_in, const int* in_sizes, int n_in,
                              void* d_out, int out_size, void* d_ws, size_t ws_size,
                              hipStream_t stream) {
    (void)in_sizes; (void)n_in; (void)ws_size; (void)out_size;

    const float* x         = (const float*)d_in[0];
    const float* edge_attr = (const float*)d_in[1];
    const int*   edge_idx  = (const int*)  d_in[2];
    const float* eW1 = (const float*)d_in[3];
    const float* eb1 = (const float*)d_in[4];
    const float* eW2 = (const float*)d_in[5];
    const float* eb2 = (const float*)d_in[6];
    const float* elg = (const float*)d_in[7];
    const float* elb = (const float*)d_in[8];
    const float* nW1 = (const float*)d_in[9];
    const float* nb1 = (const float*)d_in[10];
    const float* nW2 = (const float*)d_in[11];
    const float* nb2 = (const float*)d_in[12];
    const float* nlg = (const float*)d_in[13];
    const float* nlb = (const float*)d_in[14];

    float* out       = (float*)d_out;
    float* nodes_out = out;                        // doubles as agg accumulator
    float* edges_out = out + (size_t)NNODES * D;

    __bf16* ws = (__bf16*)d_ws;

    prep_weights<<<(WS_ELEMS + 255) / 256, 256, 0, stream>>>(eW1, eW2, nW1, nW2, ws);

    hipMemsetAsync(nodes_out, 0, (size_t)NNODES * D * sizeof(float), stream);

    edge_kernel<<<NEDGES / TE, BLK, 0, stream>>>(
        x, edge_attr, edge_idx,
        ws + EW1T_OFF, eb1, ws + EW2T_OFF, eb2, elg, elb,
        edges_out, nodes_out);

    node_kernel<<<(NNODES + TE - 1) / TE, BLK, 0, stream>>>(
        x, nodes_out,
        ws + NW1T_OFF, nb1, ws + NW2T_OFF, nb2, nlg, nlb,
        nodes_out);
}